// Round 1
// baseline (379.982 us; speedup 1.0000x reference)
//
#include <hip/hip_runtime.h>
#include <math.h>

#define NG    64
#define NPG   2048
#define NTOT  (NG*NPG)     // 131072
#define D     256
#define ZD    64
#define PD    128
#define MH    256

// ---------- helpers ----------
__device__ __forceinline__ unsigned short f2bf(float f){
  unsigned u = __float_as_uint(f);
  unsigned r = u + 0x7FFFu + ((u >> 16) & 1u);
  return (unsigned short)(r >> 16);
}
__device__ __forceinline__ float bf2f(unsigned short s){
  return __uint_as_float(((unsigned)s) << 16);
}
__device__ __forceinline__ float gelu_f(float x){
  // tanh-form GELU, max abs err ~3e-3 (threshold 6.3e-2)
  float t = 0.7978845608028654f * fmaf(0.044715f * x, x * x, x);
  float e = __expf(2.0f * t);
  float th = 1.0f - 2.0f / (e + 1.0f);   // robust at e->inf
  return 0.5f * x * (1.0f + th);
}

// ---------- K1: adaptive pool x [131072,256] -> pooled [64,128] ----------
__global__ void pool_kernel(const float* __restrict__ x, float* __restrict__ pooled){
  int b  = blockIdx.x >> 4;
  int oh = blockIdx.x & 15;
  int tid = threadIdx.x;
  int c4 = tid & 63;       // float4 column index (cols 4*c4..4*c4+3)
  int rq = tid >> 6;       // row phase 0..3
  const float4* x4 = (const float4*)x;
  size_t base = (size_t)(b * NPG + oh * 128) * 64;
  float4 acc = make_float4(0.f, 0.f, 0.f, 0.f);
  #pragma unroll 8
  for (int i = 0; i < 32; i++){
    float4 v = x4[base + (size_t)(rq + i * 4) * 64 + c4];
    acc.x += v.x; acc.y += v.y; acc.z += v.z; acc.w += v.w;
  }
  __shared__ float red[256];
  red[tid] = acc.x + acc.y + acc.z + acc.w;
  __syncthreads();
  if (tid < 8){
    float s = 0.f;
    #pragma unroll
    for (int w = 0; w < 4; w++)
      #pragma unroll
      for (int j = 0; j < 8; j++)
        s += red[w * 64 + tid * 8 + j];
    pooled[b * PD + oh * 8 + tid] = s * (1.0f / 4096.0f);
  }
}

// ---------- K2: z stats: St[dim][graph] (transposed sums), Cpart partials of Z^T Z ----------
__global__ void zstat_kernel(const float* __restrict__ z, float* __restrict__ St,
                             float* __restrict__ Cpart){
  int blk = blockIdx.x;            // 512 blocks, 256 rows each
  int g = blk >> 3;
  int tid = threadIdx.x;
  int lane = tid & 63, wave = tid >> 6;
  int row0 = g * NPG + (blk & 7) * 256 + wave * 64;
  const float* zp = z + (size_t)row0 * ZD + lane;

  float acc[64];
  #pragma unroll
  for (int p = 0; p < 64; p++) acc[p] = 0.f;
  float sac = 0.f;

  for (int r = 0; r < 64; r++){
    float zl = zp[(size_t)r * ZD];
    sac += zl;
    #pragma unroll
    for (int p = 0; p < 64; p++){
      float zpv = __uint_as_float(__builtin_amdgcn_readlane(__float_as_uint(zl), p));
      acc[p] = fmaf(zpv, zl, acc[p]);
    }
  }
  // per-graph sums, transposed: St[dim*64 + g]
  atomicAdd(&St[lane * 64 + g], sac);

  // block-reduce C across 4 waves via LDS, then atomicAdd into Cpart slot blk>>2
  __shared__ float red[4 * 4096];   // 64 KB
  #pragma unroll
  for (int p = 0; p < 64; p++) red[wave * 4096 + p * 64 + lane] = acc[p];
  __syncthreads();
  float* dst = Cpart + (size_t)(blk >> 2) * 4096;
  for (int i = tid; i < 4096; i += 256){
    float s2 = red[i] + red[4096 + i] + red[8192 + i] + red[12288 + i];
    atomicAdd(&dst[i], s2);
  }
}

// ---------- K2b: reduce 128 Cpart slots -> C[4096] ----------
__global__ void creduce_kernel(const float* __restrict__ Cpart, float* __restrict__ C){
  int o = blockIdx.x * 256 + threadIdx.x;     // 16 x-blocks
  int b0 = blockIdx.y * 32;                   // 4 y-blocks
  float s = 0.f;
  #pragma unroll 8
  for (int b = b0; b < b0 + 32; b++) s += Cpart[(size_t)b * 4096 + o];
  atomicAdd(&C[o], s);
}

// ---------- K3a: G[b][j] = b1[j] + pooled[b] . W1_bot[:,j] ----------
__global__ void gmat_kernel(const float* __restrict__ pooled, const float* __restrict__ W1,
                            const float* __restrict__ b1, float* __restrict__ G){
  int b = blockIdx.x; int j = threadIdx.x;
  __shared__ float p[PD];
  if (j < PD) p[j] = pooled[b * PD + j];
  __syncthreads();
  float s = b1[j];
  #pragma unroll 8
  for (int k = 0; k < PD; k++) s = fmaf(p[k], W1[(size_t)(ZD + k) * MH + j], s);
  G[b * MH + j] = s;
}

// ---------- K3b: analytic BN stats -> a[j], cprime[b][j] ----------
__global__ void stats_kernel(const float* __restrict__ C, const float* __restrict__ St,
                             const float* __restrict__ G, const float* __restrict__ W1,
                             const float* __restrict__ gamma, const float* __restrict__ beta,
                             float* __restrict__ a_out, float* __restrict__ cprime){
  int j = blockIdx.x * 4 + (threadIdx.x >> 6);   // 64 blocks x 4 cols
  int p = threadIdx.x & 63;                      // lane = row index / graph index
  float wl = W1[(size_t)p * MH + j];             // w_j[p]
  float t1 = 0.f, t2 = 0.f;
  #pragma unroll
  for (int q = 0; q < 64; q++){
    float wq = __uint_as_float(__builtin_amdgcn_readlane(__float_as_uint(wl), q));
    t1 = fmaf(C [q * 64 + p], wq, t1);   // (C w)_p  (C symmetric)
    t2 = fmaf(St[q * 64 + p], wq, t2);   // S_p . w
  }
  float g = G[p * MH + j];
  float v_wcw = wl * t1;
  float v_gs  = g * t2;
  float v_s   = t2;
  float v_g   = g;
  float v_g2  = g * g;
  #pragma unroll
  for (int off = 32; off; off >>= 1){
    v_wcw += __shfl_xor(v_wcw, off);
    v_gs  += __shfl_xor(v_gs , off);
    v_s   += __shfl_xor(v_s  , off);
    v_g   += __shfl_xor(v_g  , off);
    v_g2  += __shfl_xor(v_g2 , off);
  }
  const float invN = 1.0f / (float)NTOT;
  float mean = v_s * invN + v_g * (1.0f / 64.0f);
  float eh2  = v_wcw * invN + 2.0f * invN * v_gs + v_g2 * (1.0f / 64.0f);
  float var  = eh2 - mean * mean;
  float aj = gamma[j] * rsqrtf(var + 1e-5f);
  if (p == 0) a_out[j] = aj;
  cprime[p * MH + j] = fmaf(aj, g, beta[j] - aj * mean);
}

// ---------- K4: fused  u=z@W1_top -> BN affine -> GELU -> @W2 + b2 ----------
__launch_bounds__(256, 3)
__global__ void final_kernel(const float* __restrict__ z, const float* __restrict__ W1,
                             const float* __restrict__ a_arr, const float* __restrict__ cp,
                             const float* __restrict__ W2, const float* __restrict__ b2,
                             float* __restrict__ out){
  __shared__ unsigned short w1t[64 * 256];  // 32 KB, bf16
  __shared__ float zt[64 * 64];             // 16 KB, [k][m]
  int tid = threadIdx.x;
  int n0 = blockIdx.x * 64;
  int g = n0 >> 11;

  for (int i = tid; i < 64 * 256; i += 256) w1t[i] = f2bf(W1[i]);

  const float4* z4 = (const float4*)z + (size_t)n0 * 16;
  for (int i = tid; i < 1024; i += 256){
    int m = i >> 4, k4 = i & 15;
    float4 v = z4[m * 16 + k4];
    zt[(k4 * 4 + 0) * 64 + m] = v.x;
    zt[(k4 * 4 + 1) * 64 + m] = v.y;
    zt[(k4 * 4 + 2) * 64 + m] = v.z;
    zt[(k4 * 4 + 3) * 64 + m] = v.w;
  }
  __syncthreads();

  int cid = tid & 63, nid = tid >> 6;
  int j0 = cid * 4, m0 = nid * 16;

  float acc[16][4];
  #pragma unroll
  for (int mm = 0; mm < 16; mm++)
    #pragma unroll
    for (int c = 0; c < 4; c++) acc[mm][c] = 0.f;

  #pragma unroll 4
  for (int k = 0; k < 64; k++){
    ushort4 wu = *(const ushort4*)&w1t[k * 256 + j0];
    float w0 = bf2f(wu.x), w1 = bf2f(wu.y), w2 = bf2f(wu.z), w3 = bf2f(wu.w);
    const float4* zr = (const float4*)&zt[k * 64 + m0];
    float4 za = zr[0], zb = zr[1], zc = zr[2], zd = zr[3];
    float zm[16] = {za.x, za.y, za.z, za.w, zb.x, zb.y, zb.z, zb.w,
                    zc.x, zc.y, zc.z, zc.w, zd.x, zd.y, zd.z, zd.w};
    #pragma unroll
    for (int mm = 0; mm < 16; mm++){
      acc[mm][0] = fmaf(zm[mm], w0, acc[mm][0]);
      acc[mm][1] = fmaf(zm[mm], w1, acc[mm][1]);
      acc[mm][2] = fmaf(zm[mm], w2, acc[mm][2]);
      acc[mm][3] = fmaf(zm[mm], w3, acc[mm][3]);
    }
  }

  // epilogue
  float4 av  = *(const float4*)&a_arr[j0];
  float4 cpv = *(const float4*)&cp[g * MH + j0];
  float ac[4] = {av.x, av.y, av.z, av.w};
  float cv[4] = {cpv.x, cpv.y, cpv.z, cpv.w};
  float w2r[4][3];
  #pragma unroll
  for (int c = 0; c < 4; c++)
    #pragma unroll
    for (int m = 0; m < 3; m++) w2r[c][m] = W2[(j0 + c) * 3 + m];
  float b20 = b2[0], b21 = b2[1], b22 = b2[2];

  #pragma unroll
  for (int mm = 0; mm < 16; mm++){
    float o0 = 0.f, o1 = 0.f, o2 = 0.f;
    #pragma unroll
    for (int c = 0; c < 4; c++){
      float h  = fmaf(ac[c], acc[mm][c], cv[c]);
      float ge = gelu_f(h);
      o0 = fmaf(ge, w2r[c][0], o0);
      o1 = fmaf(ge, w2r[c][1], o1);
      o2 = fmaf(ge, w2r[c][2], o2);
    }
    #pragma unroll
    for (int off = 32; off; off >>= 1){
      o0 += __shfl_xor(o0, off);
      o1 += __shfl_xor(o1, off);
      o2 += __shfl_xor(o2, off);
    }
    if (cid == 0){
      float* op = out + (size_t)(n0 + m0 + mm) * 3;
      op[0] = o0 + b20; op[1] = o1 + b21; op[2] = o2 + b22;
    }
  }
}

// ---------- launch ----------
extern "C" void kernel_launch(void* const* d_in, const int* in_sizes, int n_in,
                              void* d_out, int out_size, void* d_ws, size_t ws_size,
                              hipStream_t stream){
  (void)in_sizes; (void)n_in; (void)out_size; (void)ws_size;
  const float* x     = (const float*)d_in[0];
  // d_in[1] = batch: unused (node i -> graph i>>11 by construction)
  const float* z     = (const float*)d_in[2];
  const float* W1    = (const float*)d_in[3];
  const float* b1    = (const float*)d_in[4];
  const float* gamma = (const float*)d_in[5];
  const float* beta  = (const float*)d_in[6];
  const float* W2    = (const float*)d_in[7];
  const float* b2    = (const float*)d_in[8];
  float* out = (float*)d_out;

  float* W = (float*)d_ws;
  float* pooled = W;             // 8192
  float* St     = W + 8192;      // 4096  (S transposed [dim][graph])
  float* C      = W + 12288;     // 4096
  float* G      = W + 16384;     // 16384
  float* Aj     = W + 32768;     // 256
  float* CP     = W + 33024;     // 16384
  float* Cpart  = W + 49408;     // 128*4096 = 524288
  // total 573,696 floats = 2.29 MB of ws

  // zero atomic targets (ws is poisoned 0xAA before every launch)
  hipMemsetAsync((char*)d_ws + 8192 * 4, 0, 8192 * 4, stream);            // St + C
  hipMemsetAsync((char*)d_ws + (size_t)49408 * 4, 0, (size_t)524288 * 4, stream); // Cpart

  pool_kernel  <<<dim3(NG * 16), dim3(256), 0, stream>>>(x, pooled);
  zstat_kernel <<<dim3(512),     dim3(256), 0, stream>>>(z, St, Cpart);
  creduce_kernel<<<dim3(16, 4),  dim3(256), 0, stream>>>(Cpart, C);
  gmat_kernel  <<<dim3(NG),      dim3(256), 0, stream>>>(pooled, W1, b1, G);
  stats_kernel <<<dim3(64),      dim3(256), 0, stream>>>(C, St, G, W1, gamma, beta, Aj, CP);
  final_kernel <<<dim3(NTOT / 64), dim3(256), 0, stream>>>(z, W1, Aj, CP, W2, b2, out);
}

// Round 2
// 311.064 us; speedup vs baseline: 1.2216x; 1.2216x over previous
//
#include <hip/hip_runtime.h>
#include <math.h>

#define NG    64
#define NPG   2048
#define NTOT  (NG*NPG)     // 131072
#define D     256
#define ZD    64
#define PD    128
#define MH    256

typedef __attribute__((ext_vector_type(8))) short bf16x8;
typedef __attribute__((ext_vector_type(4))) float f32x4;

// ---------- helpers ----------
__device__ __forceinline__ unsigned short f2bf(float f){
  unsigned u = __float_as_uint(f);
  unsigned r = u + 0x7FFFu + ((u >> 16) & 1u);
  return (unsigned short)(r >> 16);
}
__device__ __forceinline__ float bf2f(unsigned short s){
  return __uint_as_float(((unsigned)s) << 16);
}
__device__ __forceinline__ float gelu_f(float x){
  float t = 0.7978845608028654f * fmaf(0.044715f * x, x * x, x);
  float e = __expf(2.0f * t);
  float th = 1.0f - 2.0f / (e + 1.0f);   // robust at e->inf
  return 0.5f * x * (1.0f + th);
}

// ---------- K1: adaptive pool x [131072,256] -> pooled [64,128] ----------
__global__ void pool_kernel(const float* __restrict__ x, float* __restrict__ pooled){
  int b  = blockIdx.x >> 4;
  int oh = blockIdx.x & 15;
  int tid = threadIdx.x;
  int c4 = tid & 63;
  int rq = tid >> 6;
  const float4* x4 = (const float4*)x;
  size_t base = (size_t)(b * NPG + oh * 128) * 64;
  float4 acc = make_float4(0.f, 0.f, 0.f, 0.f);
  #pragma unroll 8
  for (int i = 0; i < 32; i++){
    float4 v = x4[base + (size_t)(rq + i * 4) * 64 + c4];
    acc.x += v.x; acc.y += v.y; acc.z += v.z; acc.w += v.w;
  }
  __shared__ float red[256];
  red[tid] = acc.x + acc.y + acc.z + acc.w;
  __syncthreads();
  if (tid < 8){
    float s = 0.f;
    #pragma unroll
    for (int w = 0; w < 4; w++)
      #pragma unroll
      for (int j = 0; j < 8; j++)
        s += red[w * 64 + tid * 8 + j];
    pooled[b * PD + oh * 8 + tid] = s * (1.0f / 4096.0f);
  }
}

// ---------- K2: MFMA zstat: St[dim][graph], Cpart[blk] partial of Z^T Z ----------
// 128 blocks: 2 per graph, each handles 1024 rows in 4 chunks of 256.
__launch_bounds__(256, 1)
__global__ void zstat_kernel(const float* __restrict__ z, float* __restrict__ St,
                             float* __restrict__ Cpart){
  __shared__ __align__(16) unsigned short zt[64 * 264];  // [dim][row], pad 8
  __shared__ float Cred[4][4096];
  int tid = threadIdx.x;
  int lane = tid & 63, wave = tid >> 6;
  int col = lane & 15, quad = lane >> 4;
  int g = blockIdx.x >> 1;
  int half = blockIdx.x & 1;
  const float4* z4 = (const float4*)z + ((size_t)g * 2048 + half * 1024) * 16;
  int d4 = tid & 15;   // fixed float4 column per thread

  f32x4 acc[4][4];
  #pragma unroll
  for (int a = 0; a < 4; a++)
    #pragma unroll
    for (int b = 0; b < 4; b++) acc[a][b] = (f32x4)(0.f);
  float s0 = 0.f, s1 = 0.f, s2 = 0.f, s3 = 0.f;

  for (int ch = 0; ch < 4; ch++){
    #pragma unroll
    for (int i = 0; i < 16; i++){
      int idx = tid + i * 256;       // 4096 = 256 rows x 16 f4cols
      int m = idx >> 4;
      float4 v = z4[ch * 4096 + idx];
      s0 += v.x; s1 += v.y; s2 += v.z; s3 += v.w;
      zt[(d4 * 4 + 0) * 264 + m] = f2bf(v.x);
      zt[(d4 * 4 + 1) * 264 + m] = f2bf(v.y);
      zt[(d4 * 4 + 2) * 264 + m] = f2bf(v.z);
      zt[(d4 * 4 + 3) * 264 + m] = f2bf(v.w);
    }
    __syncthreads();
    // wave contracts rows [wave*64, wave*64+64)
    #pragma unroll
    for (int ks = 0; ks < 2; ks++){
      int k0 = wave * 64 + ks * 32;
      bf16x8 fr[4];
      #pragma unroll
      for (int t = 0; t < 4; t++)
        fr[t] = *(const bf16x8*)&zt[(t * 16 + col) * 264 + k0 + quad * 8];
      #pragma unroll
      for (int mt = 0; mt < 4; mt++)
        #pragma unroll
        for (int nt = 0; nt < 4; nt++)
          acc[mt][nt] = __builtin_amdgcn_mfma_f32_16x16x32_bf16(fr[mt], fr[nt], acc[mt][nt], 0, 0, 0);
    }
    __syncthreads();
  }

  // per-graph sums: reduce the 4 quad-siblings per wave, then atomics
  s0 += __shfl_xor(s0, 16); s0 += __shfl_xor(s0, 32);
  s1 += __shfl_xor(s1, 16); s1 += __shfl_xor(s1, 32);
  s2 += __shfl_xor(s2, 16); s2 += __shfl_xor(s2, 32);
  s3 += __shfl_xor(s3, 16); s3 += __shfl_xor(s3, 32);
  if (quad == 0){
    atomicAdd(&St[(d4 * 4 + 0) * 64 + g], s0);
    atomicAdd(&St[(d4 * 4 + 1) * 64 + g], s1);
    atomicAdd(&St[(d4 * 4 + 2) * 64 + g], s2);
    atomicAdd(&St[(d4 * 4 + 3) * 64 + g], s3);
  }

  // block-reduce C partials
  #pragma unroll
  for (int mt = 0; mt < 4; mt++)
    #pragma unroll
    for (int nt = 0; nt < 4; nt++)
      #pragma unroll
      for (int r = 0; r < 4; r++){
        int p = mt * 16 + quad * 4 + r;
        int q = nt * 16 + col;
        Cred[wave][p * 64 + q] = acc[mt][nt][r];
      }
  __syncthreads();
  float* dst = Cpart + (size_t)blockIdx.x * 4096;
  for (int f = tid; f < 4096; f += 256)
    dst[f] = Cred[0][f] + Cred[1][f] + Cred[2][f] + Cred[3][f];
}

// ---------- K2b: reduce 128 Cpart slots -> C[4096] ----------
__global__ void creduce_kernel(const float* __restrict__ Cpart, float* __restrict__ C){
  int o = blockIdx.x * 256 + threadIdx.x;   // 16 blocks
  float s = 0.f;
  #pragma unroll 8
  for (int b = 0; b < 128; b++) s += Cpart[(size_t)b * 4096 + o];
  C[o] = s;
}

// ---------- K3a: G[b][j] = b1[j] + pooled[b] . W1_bot[:,j] ----------
__global__ void gmat_kernel(const float* __restrict__ pooled, const float* __restrict__ W1,
                            const float* __restrict__ b1, float* __restrict__ G){
  int b = blockIdx.x; int j = threadIdx.x;
  __shared__ float p[PD];
  if (j < PD) p[j] = pooled[b * PD + j];
  __syncthreads();
  float s = b1[j];
  #pragma unroll 8
  for (int k = 0; k < PD; k++) s = fmaf(p[k], W1[(size_t)(ZD + k) * MH + j], s);
  G[b * MH + j] = s;
}

// ---------- K3b: analytic BN stats -> a[j], cprime[b][j] ----------
__global__ void stats_kernel(const float* __restrict__ C, const float* __restrict__ St,
                             const float* __restrict__ G, const float* __restrict__ W1,
                             const float* __restrict__ gamma, const float* __restrict__ beta,
                             float* __restrict__ a_out, float* __restrict__ cprime){
  int j = blockIdx.x * 4 + (threadIdx.x >> 6);
  int p = threadIdx.x & 63;
  float wl = W1[(size_t)p * MH + j];
  float t1 = 0.f, t2 = 0.f;
  #pragma unroll
  for (int q = 0; q < 64; q++){
    float wq = __uint_as_float(__builtin_amdgcn_readlane(__float_as_uint(wl), q));
    t1 = fmaf(C [q * 64 + p], wq, t1);
    t2 = fmaf(St[q * 64 + p], wq, t2);
  }
  float g = G[p * MH + j];
  float v_wcw = wl * t1;
  float v_gs  = g * t2;
  float v_s   = t2;
  float v_g   = g;
  float v_g2  = g * g;
  #pragma unroll
  for (int off = 32; off; off >>= 1){
    v_wcw += __shfl_xor(v_wcw, off);
    v_gs  += __shfl_xor(v_gs , off);
    v_s   += __shfl_xor(v_s  , off);
    v_g   += __shfl_xor(v_g  , off);
    v_g2  += __shfl_xor(v_g2 , off);
  }
  const float invN = 1.0f / (float)NTOT;
  float mean = v_s * invN + v_g * (1.0f / 64.0f);
  float eh2  = v_wcw * invN + 2.0f * invN * v_gs + v_g2 * (1.0f / 64.0f);
  float var  = eh2 - mean * mean;
  float aj = gamma[j] * rsqrtf(var + 1e-5f);
  if (p == 0) a_out[j] = aj;
  cprime[p * MH + j] = fmaf(aj, g, beta[j] - aj * mean);
}

// ---------- K4: MFMA fused  u=z@W1_top -> BN affine -> GELU -> @W2 + b2 ----------
// block: 128 nodes x 256 j. z split hi/lo bf16 -> K=128 vs replicated W1^T.
__launch_bounds__(256, 2)
__global__ void final_kernel(const float* __restrict__ z, const float* __restrict__ W1,
                             const float* __restrict__ Aj, const float* __restrict__ cp,
                             const float* __restrict__ W2, const float* __restrict__ b2,
                             float* __restrict__ out){
  __shared__ __align__(16) unsigned short zt[128 * 136];  // [m][k0..127 = hi|lo], pad 8
  __shared__ __align__(16) unsigned short Wt[256 * 72];   // [j][k0..63], pad 8
  __shared__ float slab[2][384];
  int tid = threadIdx.x;
  int n0 = blockIdx.x * 128;
  int g = blockIdx.x >> 4;

  // stage W1^T (rows 0..63 of W1) as bf16
  const float4* W14 = (const float4*)W1;
  #pragma unroll
  for (int i = 0; i < 16; i++){
    int idx = tid + i * 256;           // 4096 = 64 k x 64 j4
    int k = idx >> 6, j4 = idx & 63;
    float4 v = W14[k * 64 + j4];
    Wt[(j4 * 4 + 0) * 72 + k] = f2bf(v.x);
    Wt[(j4 * 4 + 1) * 72 + k] = f2bf(v.y);
    Wt[(j4 * 4 + 2) * 72 + k] = f2bf(v.z);
    Wt[(j4 * 4 + 3) * 72 + k] = f2bf(v.w);
  }
  // stage z tile hi/lo
  const float4* z4 = (const float4*)z + (size_t)n0 * 16;
  #pragma unroll
  for (int i = 0; i < 8; i++){
    int idx = tid + i * 256;           // 2048 = 128 m x 16 d4
    int m = idx >> 4, d4 = idx & 15;
    float4 v = z4[idx];
    ushort4 h, l;
    h.x = f2bf(v.x); l.x = f2bf(v.x - bf2f(h.x));
    h.y = f2bf(v.y); l.y = f2bf(v.y - bf2f(h.y));
    h.z = f2bf(v.z); l.z = f2bf(v.z - bf2f(h.z));
    h.w = f2bf(v.w); l.w = f2bf(v.w - bf2f(h.w));
    *(ushort4*)&zt[m * 136 + d4 * 4]      = h;
    *(ushort4*)&zt[m * 136 + 64 + d4 * 4] = l;
  }
  __syncthreads();

  int lane = tid & 63, wave = tid >> 6;
  int wm = wave & 1, wn = wave >> 1;
  int col = lane & 15, quad = lane >> 4;
  int mbase = wm * 64, nbase = wn * 128;

  f32x4 acc[4][8];
  #pragma unroll
  for (int mt = 0; mt < 4; mt++)
    #pragma unroll
    for (int nt = 0; nt < 8; nt++) acc[mt][nt] = (f32x4)(0.f);

  #pragma unroll
  for (int ks = 0; ks < 4; ks++){
    int k0 = ks * 32;        // A: k over 0..127 (hi|lo); B: k0&63 (W replicated)
    bf16x8 af[4], bfr[8];
    #pragma unroll
    for (int mt = 0; mt < 4; mt++)
      af[mt] = *(const bf16x8*)&zt[(mbase + mt * 16 + col) * 136 + k0 + quad * 8];
    #pragma unroll
    for (int nt = 0; nt < 8; nt++)
      bfr[nt] = *(const bf16x8*)&Wt[(nbase + nt * 16 + col) * 72 + (k0 & 63) + quad * 8];
    #pragma unroll
    for (int mt = 0; mt < 4; mt++)
      #pragma unroll
      for (int nt = 0; nt < 8; nt++)
        acc[mt][nt] = __builtin_amdgcn_mfma_f32_16x16x32_bf16(af[mt], bfr[nt], acc[mt][nt], 0, 0, 0);
  }

  // per-lane j constants
  float aj[8], cj[8], w2a[8], w2b[8], w2c[8];
  #pragma unroll
  for (int nt = 0; nt < 8; nt++){
    int j = nbase + nt * 16 + col;
    aj[nt] = Aj[j];
    cj[nt] = cp[g * MH + j];
    w2a[nt] = W2[j * 3 + 0];
    w2b[nt] = W2[j * 3 + 1];
    w2c[nt] = W2[j * 3 + 2];
  }

  // epilogue: BN affine -> GELU -> dot W2, reduce over j
  #pragma unroll
  for (int mt = 0; mt < 4; mt++){
    #pragma unroll
    for (int r = 0; r < 4; r++){
      float o0 = 0.f, o1 = 0.f, o2 = 0.f;
      #pragma unroll
      for (int nt = 0; nt < 8; nt++){
        float h  = fmaf(aj[nt], acc[mt][nt][r], cj[nt]);
        float ge = gelu_f(h);
        o0 = fmaf(ge, w2a[nt], o0);
        o1 = fmaf(ge, w2b[nt], o1);
        o2 = fmaf(ge, w2c[nt], o2);
      }
      #pragma unroll
      for (int off = 8; off; off >>= 1){
        o0 += __shfl_xor(o0, off);
        o1 += __shfl_xor(o1, off);
        o2 += __shfl_xor(o2, off);
      }
      if (col == 0){
        int node = mbase + mt * 16 + quad * 4 + r;
        slab[wn][node * 3 + 0] = o0;
        slab[wn][node * 3 + 1] = o1;
        slab[wn][node * 3 + 2] = o2;
      }
    }
  }
  __syncthreads();
  float b2v[3] = {b2[0], b2[1], b2[2]};
  for (int f = tid; f < 384; f += 256)
    out[(size_t)blockIdx.x * 384 + f] = slab[0][f] + slab[1][f] + b2v[f % 3];
}

// ---------- launch ----------
extern "C" void kernel_launch(void* const* d_in, const int* in_sizes, int n_in,
                              void* d_out, int out_size, void* d_ws, size_t ws_size,
                              hipStream_t stream){
  (void)in_sizes; (void)n_in; (void)out_size; (void)ws_size;
  const float* x     = (const float*)d_in[0];
  const float* z     = (const float*)d_in[2];
  const float* W1    = (const float*)d_in[3];
  const float* b1    = (const float*)d_in[4];
  const float* gamma = (const float*)d_in[5];
  const float* beta  = (const float*)d_in[6];
  const float* W2    = (const float*)d_in[7];
  const float* b2    = (const float*)d_in[8];
  float* out = (float*)d_out;

  float* W = (float*)d_ws;
  float* pooled = W;             // 8192
  float* St     = W + 8192;      // 4096
  float* C      = W + 12288;     // 4096
  float* G      = W + 16384;     // 16384
  float* Aj     = W + 32768;     // 256
  float* CP     = W + 33024;     // 16384
  float* Cpart  = W + 49408;     // 128*4096 = 524288

  // zero St only (Cpart/C fully written now)
  hipMemsetAsync((char*)d_ws + 8192 * 4, 0, 4096 * 4, stream);

  pool_kernel   <<<dim3(NG * 16),   dim3(256), 0, stream>>>(x, pooled);
  zstat_kernel  <<<dim3(128),       dim3(256), 0, stream>>>(z, St, Cpart);
  creduce_kernel<<<dim3(16),        dim3(256), 0, stream>>>(Cpart, C);
  gmat_kernel   <<<dim3(NG),        dim3(256), 0, stream>>>(pooled, W1, b1, G);
  stats_kernel  <<<dim3(64),        dim3(256), 0, stream>>>(C, St, G, W1, gamma, beta, Aj, CP);
  final_kernel  <<<dim3(NTOT / 128), dim3(256), 0, stream>>>(z, W1, Aj, CP, W2, b2, out);
}

// Round 3
// 282.493 us; speedup vs baseline: 1.3451x; 1.1011x over previous
//
#include <hip/hip_runtime.h>
#include <math.h>

#define NG    64
#define NPG   2048
#define NTOT  (NG*NPG)     // 131072
#define ZD    64
#define PD    128
#define MH    256

typedef __attribute__((ext_vector_type(8))) short bf16x8;
typedef __attribute__((ext_vector_type(4))) float f32x4;

// ---------- helpers ----------
__device__ __forceinline__ unsigned short f2bf(float f){
  unsigned u = __float_as_uint(f);
  unsigned r = u + 0x7FFFu + ((u >> 16) & 1u);
  return (unsigned short)(r >> 16);
}
__device__ __forceinline__ float bf2f(unsigned short s){
  return __uint_as_float(((unsigned)s) << 16);
}
__device__ __forceinline__ float gelu_f(float x){
  float t = 0.7978845608028654f * fmaf(0.044715f * x, x * x, x);
  float e = __expf(2.0f * t);
  float th = 1.0f - 2.0f / (e + 1.0f);   // robust at e->inf
  return 0.5f * x * (1.0f + th);
}

// ---------- K1: fused pool (blocks 256..1279) + zstat (blocks 0..255) ----------
// zstat: 4 blocks/graph, 512 rows each, MFMA Z^T Z partials -> atomicAdd C; St atomics.
// pool: adaptive pool x [131072,256] -> pooled [64,128].
__launch_bounds__(256)
__global__ void k1_pool_zstat(const float* __restrict__ x, const float* __restrict__ z,
                              float* __restrict__ pooled, float* __restrict__ St,
                              float* __restrict__ C){
  __shared__ __align__(16) unsigned short s_zt[64 * 264];  // 33792 B
  __shared__ float s_cred[4096];                           // 16384 B (pool reuses first 256)
  int tid = threadIdx.x;

  if (blockIdx.x >= 256){
    // ---- pool ----
    int bi = blockIdx.x - 256;
    int b  = bi >> 4;
    int oh = bi & 15;
    int c4 = tid & 63;
    int rq = tid >> 6;
    const float4* x4 = (const float4*)x;
    size_t base = (size_t)(b * NPG + oh * 128) * 64;
    float4 acc = make_float4(0.f, 0.f, 0.f, 0.f);
    #pragma unroll 8
    for (int i = 0; i < 32; i++){
      float4 v = x4[base + (size_t)(rq + i * 4) * 64 + c4];
      acc.x += v.x; acc.y += v.y; acc.z += v.z; acc.w += v.w;
    }
    s_cred[tid] = acc.x + acc.y + acc.z + acc.w;
    __syncthreads();
    if (tid < 8){
      float s = 0.f;
      #pragma unroll
      for (int w = 0; w < 4; w++)
        #pragma unroll
        for (int j = 0; j < 8; j++)
          s += s_cred[w * 64 + tid * 8 + j];
      pooled[b * PD + oh * 8 + tid] = s * (1.0f / 4096.0f);
    }
    return;
  }

  // ---- zstat ----
  int blk = blockIdx.x;           // 0..255
  int g = blk >> 2, q4 = blk & 3;
  int lane = tid & 63, wave = tid >> 6;
  int col = lane & 15, quad = lane >> 4;
  const float4* z4 = (const float4*)z + ((size_t)g * 2048 + q4 * 512) * 16;
  int d4 = tid & 15;

  f32x4 acc[4][4];
  #pragma unroll
  for (int a = 0; a < 4; a++)
    #pragma unroll
    for (int b = 0; b < 4; b++) acc[a][b] = (f32x4)(0.f);
  float s0 = 0.f, s1 = 0.f, s2 = 0.f, s3 = 0.f;

  for (int ch = 0; ch < 2; ch++){
    #pragma unroll
    for (int i = 0; i < 16; i++){
      int idx = tid + i * 256;       // 4096 = 256 rows x 16 f4cols
      int m = idx >> 4;
      float4 v = z4[ch * 4096 + idx];
      s0 += v.x; s1 += v.y; s2 += v.z; s3 += v.w;
      s_zt[(d4 * 4 + 0) * 264 + m] = f2bf(v.x);
      s_zt[(d4 * 4 + 1) * 264 + m] = f2bf(v.y);
      s_zt[(d4 * 4 + 2) * 264 + m] = f2bf(v.z);
      s_zt[(d4 * 4 + 3) * 264 + m] = f2bf(v.w);
    }
    __syncthreads();
    #pragma unroll
    for (int ks = 0; ks < 2; ks++){
      int k0 = wave * 64 + ks * 32;
      bf16x8 fr[4];
      #pragma unroll
      for (int t = 0; t < 4; t++)
        fr[t] = *(const bf16x8*)&s_zt[(t * 16 + col) * 264 + k0 + quad * 8];
      #pragma unroll
      for (int mt = 0; mt < 4; mt++)
        #pragma unroll
        for (int nt = 0; nt < 4; nt++)
          acc[mt][nt] = __builtin_amdgcn_mfma_f32_16x16x32_bf16(fr[mt], fr[nt], acc[mt][nt], 0, 0, 0);
    }
    __syncthreads();
  }

  // per-graph sums (lanes with same d4 within wave: xor 16, 32)
  s0 += __shfl_xor(s0, 16); s0 += __shfl_xor(s0, 32);
  s1 += __shfl_xor(s1, 16); s1 += __shfl_xor(s1, 32);
  s2 += __shfl_xor(s2, 16); s2 += __shfl_xor(s2, 32);
  s3 += __shfl_xor(s3, 16); s3 += __shfl_xor(s3, 32);
  if (quad == 0){
    atomicAdd(&St[(d4 * 4 + 0) * 64 + g], s0);
    atomicAdd(&St[(d4 * 4 + 1) * 64 + g], s1);
    atomicAdd(&St[(d4 * 4 + 2) * 64 + g], s2);
    atomicAdd(&St[(d4 * 4 + 3) * 64 + g], s3);
  }

  // C block-reduce: sequential wave accumulate into s_cred, then atomicAdd to C
  #pragma unroll
  for (int w = 0; w < 4; w++){
    if (wave == w){
      #pragma unroll
      for (int mt = 0; mt < 4; mt++)
        #pragma unroll
        for (int nt = 0; nt < 4; nt++)
          #pragma unroll
          for (int r = 0; r < 4; r++){
            int p = mt * 16 + quad * 4 + r;
            int qc = nt * 16 + col;
            if (w == 0) s_cred[p * 64 + qc]  = acc[mt][nt][r];
            else        s_cred[p * 64 + qc] += acc[mt][nt][r];
          }
    }
    __syncthreads();
  }
  for (int f = tid; f < 4096; f += 256)
    atomicAdd(&C[f], s_cred[f]);
}

// ---------- K2: fused Wbf precompute + gmat (G in regs) + analytic BN stats ----------
__launch_bounds__(256)
__global__ void k2_stats(const float* __restrict__ pooled, const float* __restrict__ W1,
                         const float* __restrict__ b1, const float* __restrict__ gamma,
                         const float* __restrict__ beta, const float* __restrict__ C,
                         const float* __restrict__ St, float* __restrict__ Aj,
                         float* __restrict__ cprime, unsigned short* __restrict__ Wbf){
  __shared__ float pl[64 * 129];   // padded: stride 129 -> 2-way alias only
  int tid = threadIdx.x;
  int jc = tid >> 6, lane = tid & 63;
  int j = blockIdx.x * 4 + jc;

  // emit W1_top as bf16 [j][k]
  Wbf[(size_t)j * 64 + lane] = f2bf(W1[(size_t)lane * 256 + j]);

  // stage pooled
  for (int idx = tid; idx < 8192; idx += 256)
    pl[(idx >> 7) * 129 + (idx & 127)] = pooled[idx];
  __syncthreads();

  // gmat: thread (lane=b) computes G[b][j], kept in register
  float g = b1[j];
  #pragma unroll 8
  for (int k = 0; k < 128; k++)
    g = fmaf(pl[lane * 129 + k], W1[(size_t)(ZD + k) * MH + j], g);

  // stats
  float wl = W1[(size_t)lane * MH + j];    // W1_top[lane][j]
  float t1 = 0.f, t2 = 0.f;
  #pragma unroll
  for (int q = 0; q < 64; q++){
    float wq = __uint_as_float(__builtin_amdgcn_readlane(__float_as_uint(wl), q));
    t1 = fmaf(C [q * 64 + lane], wq, t1);  // (C w)_p, C symmetric
    t2 = fmaf(St[q * 64 + lane], wq, t2);  // S_p . w
  }
  float v_wcw = wl * t1;
  float v_gs  = g * t2;
  float v_s   = t2;
  float v_g   = g;
  float v_g2  = g * g;
  #pragma unroll
  for (int off = 32; off; off >>= 1){
    v_wcw += __shfl_xor(v_wcw, off);
    v_gs  += __shfl_xor(v_gs , off);
    v_s   += __shfl_xor(v_s  , off);
    v_g   += __shfl_xor(v_g  , off);
    v_g2  += __shfl_xor(v_g2 , off);
  }
  const float invN = 1.0f / (float)NTOT;
  float mean = v_s * invN + v_g * (1.0f / 64.0f);
  float eh2  = v_wcw * invN + 2.0f * invN * v_gs + v_g2 * (1.0f / 64.0f);
  float var  = eh2 - mean * mean;
  float aj = gamma[j] * rsqrtf(var + 1e-5f);
  if (lane == 0) Aj[j] = aj;
  cprime[lane * MH + j] = fmaf(aj, g, beta[j] - aj * mean);
}

// ---------- K3: MFMA fused  u=z@W1_top -> BN affine -> GELU -> @W2 + b2 ----------
// 128 nodes x 256 j per block; z split hi/lo bf16 (K=128); B-fragments direct from Wbf (L1/L2-resident).
__launch_bounds__(256, 2)
__global__ void final_kernel(const float* __restrict__ z, const unsigned short* __restrict__ Wbf,
                             const float* __restrict__ Aj, const float* __restrict__ cp,
                             const float* __restrict__ W2, const float* __restrict__ b2,
                             float* __restrict__ out){
  __shared__ __align__(16) unsigned short zt[128 * 136];  // [m][k0..127 = hi|lo], pad 8
  __shared__ float slab[2][384];
  int tid = threadIdx.x;
  int n0 = blockIdx.x * 128;
  int g = blockIdx.x >> 4;

  // stage z tile hi/lo
  const float4* z4 = (const float4*)z + (size_t)n0 * 16;
  #pragma unroll
  for (int i = 0; i < 8; i++){
    int idx = tid + i * 256;           // 2048 = 128 m x 16 d4
    int m = idx >> 4, d4 = idx & 15;
    float4 v = z4[idx];
    ushort4 h, l;
    h.x = f2bf(v.x); l.x = f2bf(v.x - bf2f(h.x));
    h.y = f2bf(v.y); l.y = f2bf(v.y - bf2f(h.y));
    h.z = f2bf(v.z); l.z = f2bf(v.z - bf2f(h.z));
    h.w = f2bf(v.w); l.w = f2bf(v.w - bf2f(h.w));
    *(ushort4*)&zt[m * 136 + d4 * 4]      = h;
    *(ushort4*)&zt[m * 136 + 64 + d4 * 4] = l;
  }
  __syncthreads();

  int lane = tid & 63, wave = tid >> 6;
  int wm = wave & 1, wn = wave >> 1;
  int col = lane & 15, quad = lane >> 4;
  int mbase = wm * 64, nbase = wn * 128;

  f32x4 acc[4][8];
  #pragma unroll
  for (int mt = 0; mt < 4; mt++)
    #pragma unroll
    for (int nt = 0; nt < 8; nt++) acc[mt][nt] = (f32x4)(0.f);

  #pragma unroll
  for (int ks = 0; ks < 4; ks++){
    int k0 = ks * 32;                  // A: k over 0..127 (hi|lo); B: (ks&1)*32
    bf16x8 af[4];
    #pragma unroll
    for (int mt = 0; mt < 4; mt++)
      af[mt] = *(const bf16x8*)&zt[(mbase + mt * 16 + col) * 136 + k0 + quad * 8];
    #pragma unroll
    for (int nt = 0; nt < 8; nt++){
      bf16x8 bv = *(const bf16x8*)&Wbf[(size_t)(nbase + nt * 16 + col) * 64 + (ks & 1) * 32 + quad * 8];
      #pragma unroll
      for (int mt = 0; mt < 4; mt++)
        acc[mt][nt] = __builtin_amdgcn_mfma_f32_16x16x32_bf16(af[mt], bv, acc[mt][nt], 0, 0, 0);
    }
  }

  // per-lane j constants
  float aj[8], cj[8], w2a[8], w2b[8], w2c[8];
  #pragma unroll
  for (int nt = 0; nt < 8; nt++){
    int j = nbase + nt * 16 + col;
    aj[nt] = Aj[j];
    cj[nt] = cp[g * MH + j];
    w2a[nt] = W2[j * 3 + 0];
    w2b[nt] = W2[j * 3 + 1];
    w2c[nt] = W2[j * 3 + 2];
  }

  // epilogue: BN affine -> GELU -> dot W2, reduce over j
  #pragma unroll
  for (int mt = 0; mt < 4; mt++){
    #pragma unroll
    for (int r = 0; r < 4; r++){
      float o0 = 0.f, o1 = 0.f, o2 = 0.f;
      #pragma unroll
      for (int nt = 0; nt < 8; nt++){
        float h  = fmaf(aj[nt], acc[mt][nt][r], cj[nt]);
        float ge = gelu_f(h);
        o0 = fmaf(ge, w2a[nt], o0);
        o1 = fmaf(ge, w2b[nt], o1);
        o2 = fmaf(ge, w2c[nt], o2);
      }
      #pragma unroll
      for (int off = 8; off; off >>= 1){
        o0 += __shfl_xor(o0, off);
        o1 += __shfl_xor(o1, off);
        o2 += __shfl_xor(o2, off);
      }
      if (col == 0){
        int node = mbase + mt * 16 + quad * 4 + r;
        slab[wn][node * 3 + 0] = o0;
        slab[wn][node * 3 + 1] = o1;
        slab[wn][node * 3 + 2] = o2;
      }
    }
  }
  __syncthreads();
  float b2v[3] = {b2[0], b2[1], b2[2]};
  for (int f = tid; f < 384; f += 256)
    out[(size_t)blockIdx.x * 384 + f] = slab[0][f] + slab[1][f] + b2v[f % 3];
}

// ---------- launch ----------
extern "C" void kernel_launch(void* const* d_in, const int* in_sizes, int n_in,
                              void* d_out, int out_size, void* d_ws, size_t ws_size,
                              hipStream_t stream){
  (void)in_sizes; (void)n_in; (void)out_size; (void)ws_size;
  const float* x     = (const float*)d_in[0];
  const float* z     = (const float*)d_in[2];
  const float* W1    = (const float*)d_in[3];
  const float* b1    = (const float*)d_in[4];
  const float* gamma = (const float*)d_in[5];
  const float* beta  = (const float*)d_in[6];
  const float* W2    = (const float*)d_in[7];
  const float* b2    = (const float*)d_in[8];
  float* out = (float*)d_out;

  float* W = (float*)d_ws;
  float* pooled = W;                         // 0     .. 8191
  float* St     = W + 8192;                  // 8192  .. 12287
  float* C      = W + 12288;                 // 12288 .. 16383
  float* Aj     = W + 16384;                 // 16384 .. 16639
  float* CP     = W + 16640;                 // 16640 .. 33023
  unsigned short* Wbf = (unsigned short*)(W + 33024);  // 16384 ushorts

  // zero St + C (contiguous 32 KB)
  hipMemsetAsync((char*)d_ws + 8192 * 4, 0, 8192 * 4, stream);

  k1_pool_zstat<<<dim3(1280), dim3(256), 0, stream>>>(x, z, pooled, St, C);
  k2_stats     <<<dim3(64),   dim3(256), 0, stream>>>(pooled, W1, b1, gamma, beta, C, St, Aj, CP, Wbf);
  final_kernel <<<dim3(NTOT / 128), dim3(256), 0, stream>>>(z, Wbf, Aj, CP, W2, b2, out);
}